// Round 6
// baseline (296.763 us; speedup 1.0000x reference)
//
#include <hip/hip_runtime.h>

#define DH 1024
#define FH 2752
#define NE 8
#define NT 1024

typedef unsigned short u16;
typedef __bf16 bf16x8 __attribute__((ext_vector_type(8)));
typedef float f32x4 __attribute__((ext_vector_type(4)));

__device__ __forceinline__ u16 f2bf(float f) {
  unsigned int u = __float_as_uint(f);
  unsigned int r = (u + 0x7fffu + ((u >> 16) & 1u)) >> 16;
  return (u16)r;
}
__device__ __forceinline__ float bf2f(u16 b) {
  return __uint_as_float(((unsigned int)b) << 16);
}
__device__ __forceinline__ bf16x8 as_bf(int4 v) {
  union { int4 i; bf16x8 b; } u; u.i = v; return u.b;
}

// ---------------- 1. gating ----------------
__global__ void gate_kernel(const float* __restrict__ x,
                            const float* __restrict__ Ws,
                            const float* __restrict__ bs,
                            u16* __restrict__ xb,
                            int* __restrict__ tki,
                            float* __restrict__ tkw) {
  int gtid = blockIdx.x * blockDim.x + threadIdx.x;
  int t = gtid >> 6;
  int lane = gtid & 63;
  if (t >= NT) return;
  const float* xr = x + (size_t)t * DH;
  float acc[NE];
#pragma unroll
  for (int e = 0; e < NE; ++e) acc[e] = 0.f;
  for (int d = lane; d < DH; d += 64) {
    float xv = xr[d];
    xb[(size_t)t * DH + d] = f2bf(xv);
    const float4* wr = (const float4*)(Ws + (size_t)d * NE);
    float4 w0 = wr[0], w1 = wr[1];
    acc[0] += xv * w0.x; acc[1] += xv * w0.y;
    acc[2] += xv * w0.z; acc[3] += xv * w0.w;
    acc[4] += xv * w1.x; acc[5] += xv * w1.y;
    acc[6] += xv * w1.z; acc[7] += xv * w1.w;
  }
#pragma unroll
  for (int e = 0; e < NE; ++e) {
#pragma unroll
    for (int off = 32; off > 0; off >>= 1)
      acc[e] += __shfl_xor(acc[e], off);
  }
  if (lane == 0) {
    float l[NE];
#pragma unroll
    for (int e = 0; e < NE; ++e) l[e] = acc[e] + bs[e];
    int i0 = 0;
#pragma unroll
    for (int e = 1; e < NE; ++e) if (l[e] > l[i0]) i0 = e;
    int i1 = (i0 == 0) ? 1 : 0;
#pragma unroll
    for (int e = 0; e < NE; ++e) if (e != i0 && l[e] > l[i1]) i1 = e;
    float e1 = __expf(l[i1] - l[i0]);
    float denom = 1.f + e1;
    tki[t*2]   = i0; tki[t*2+1] = i1;
    tkw[t*2]   = 1.f / denom;
    tkw[t*2+1] = e1 / denom;
  }
}

// ---------------- 2. expert grouping + 64-row tile table ----------------
__global__ void group_kernel(const int* __restrict__ tki,
                             int* __restrict__ offs,
                             int* __restrict__ rtok,
                             int* __restrict__ posf,
                             unsigned* __restrict__ ttab) {
  __shared__ int cnt[NE];
  __shared__ int run[NE];
  int tid = threadIdx.x;
  if (tid < NE) cnt[tid] = 0;
  __syncthreads();
  for (int t = tid; t < NT; t += blockDim.x) {
    atomicAdd(&cnt[tki[t*2]], 1);
    atomicAdd(&cnt[tki[t*2+1]], 1);
  }
  __syncthreads();
  if (tid == 0) {
    int r = 0;
    for (int e = 0; e < NE; ++e) { offs[e] = r; run[e] = r; r += cnt[e]; }
    offs[NE] = r;
    int idx = 0;
    for (int e = 0; e < NE; ++e) {
      int nt64 = (cnt[e] + 63) >> 6;
      for (int m = 0; m < nt64; ++m) ttab[idx++] = ((unsigned)e << 16) | (unsigned)m;
    }
    for (; idx < 40; ++idx) ttab[idx] = 0xFFFFFFFFu;
  }
  __syncthreads();
  for (int t = tid; t < NT; t += blockDim.x) {
    for (int k = 0; k < 2; ++k) {
      int e = tki[t*2+k];
      int p = atomicAdd(&run[e], 1);
      rtok[p] = t;
      posf[t*2+k] = p;
    }
  }
}

// ---------------- 3. gate/up projection: 1-wave blocks, barrier-free ----------------
// Each block = 1 wave, computes 64 rows x 32 cols, K=1024 in 16 bodies of BK=64.
// W fp32 loaded n-contiguous (float4), transposed via private LDS, cast to bf16.
__global__ __launch_bounds__(64, 3)
void gu_kernel(const u16* __restrict__ xb,
               const float* __restrict__ Wg,
               const float* __restrict__ Wu,
               u16* __restrict__ gbuf,
               u16* __restrict__ ubuf,
               const int* __restrict__ offs,
               const int* __restrict__ rtok,
               const unsigned* __restrict__ ttab) {
  __shared__ float bsm[32][74];

  int bid = blockIdx.x;                        // 6880 = 8 * 860
  int work = (bid & 7) * 860 + (bid >> 3);     // XCD-chunked
  int mt = work % 40;
  int c1 = work / 40;
  int ntile = c1 % 86;
  int mat = c1 / 86;                           // 0 = gate, 1 = up
  unsigned tv = ttab[mt];
  if (tv == 0xFFFFFFFFu) return;
  int e = tv >> 16, mtl = tv & 0xFFFF;
  int off0 = offs[e];
  int cnt = offs[e+1] - off0;
  int p0 = off0 + mtl * 64;
  int rmax = cnt - mtl * 64 - 1;
  int n0 = ntile * 32;

  int l = threadIdx.x;
  int nl = l & 15, hq = l >> 4;
  int kg = hq * 8;
  int ncol = (l & 7) * 4;
  int krow = l >> 3;

  const float* W = mat ? Wu : Wg;
  u16* outb = mat ? ubuf : gbuf;

  const u16* aptr[4];
#pragma unroll
  for (int mf = 0; mf < 4; ++mf) {
    int r = nl + 16*mf; if (r > rmax) r = rmax;
    aptr[mf] = xb + (size_t)rtok[p0 + r] * DH + kg;
  }
  const float* bsrc = W + (size_t)e * DH * FH + (size_t)krow * FH + n0 + ncol;

  f32x4 acc[4][2];
#pragma unroll
  for (int mf = 0; mf < 4; ++mf)
#pragma unroll
    for (int nf = 0; nf < 2; ++nf)
      acc[mf][nf] = f32x4{0.f,0.f,0.f,0.f};

  for (int body = 0; body < 16; ++body) {
    f32x4 bv[8];
#pragma unroll
    for (int i = 0; i < 8; ++i)
      bv[i] = *(const f32x4*)(bsrc + (size_t)(body*64 + i*8) * FH);
    int4 av[4][2];
#pragma unroll
    for (int mf = 0; mf < 4; ++mf) {
      av[mf][0] = *(const int4*)(aptr[mf] + body*64);
      av[mf][1] = *(const int4*)(aptr[mf] + body*64 + 32);
    }
    // transpose W tile into LDS (per-wave private; program order is the only sync)
#pragma unroll
    for (int i = 0; i < 8; ++i) {
#pragma unroll
      for (int q = 0; q < 4; ++q)
        bsm[ncol + q][i*8 + krow] = bv[i][q];
    }
#pragma unroll
    for (int h = 0; h < 2; ++h) {
      bf16x8 fb[2];
#pragma unroll
      for (int nf = 0; nf < 2; ++nf) {
#pragma unroll
        for (int j = 0; j < 4; ++j) {
          float2 p = *(const float2*)&bsm[nf*16 + nl][h*32 + kg + 2*j];
          fb[nf][2*j]   = (__bf16)p.x;
          fb[nf][2*j+1] = (__bf16)p.y;
        }
      }
#pragma unroll
      for (int mf = 0; mf < 4; ++mf) {
        bf16x8 a_ = as_bf(av[mf][h]);
        acc[mf][0] = __builtin_amdgcn_mfma_f32_16x16x32_bf16(a_, fb[0], acc[mf][0], 0,0,0);
        acc[mf][1] = __builtin_amdgcn_mfma_f32_16x16x32_bf16(a_, fb[1], acc[mf][1], 0,0,0);
      }
    }
  }

#pragma unroll
  for (int mf = 0; mf < 4; ++mf) {
    int lr0 = hq*4 + mf*16;
#pragma unroll
    for (int nf = 0; nf < 2; ++nf) {
      int col = n0 + nf*16 + nl;
#pragma unroll
      for (int q = 0; q < 4; ++q) {
        int lrow = lr0 + q;
        if (lrow <= rmax)
          outb[(size_t)(p0 + lrow) * FH + col] = f2bf(acc[mf][nf][q]);
      }
    }
  }
}

// ---------------- 4. swiglu: h = silu(g)*u ----------------
typedef u16 u16x8 __attribute__((ext_vector_type(8)));
__global__ void swiglu_kernel(const u16* __restrict__ g,
                              const u16* __restrict__ u,
                              u16* __restrict__ h) {
  size_t i = ((size_t)blockIdx.x * blockDim.x + threadIdx.x) * 8;
  u16x8 g8 = *(const u16x8*)(g + i);
  u16x8 u8 = *(const u16x8*)(u + i);
  u16x8 o;
#pragma unroll
  for (int j = 0; j < 8; ++j) {
    float gv = bf2f(g8[j]);
    float uv = bf2f(u8[j]);
    float s  = gv / (1.f + __expf(-gv));
    o[j] = f2bf(s * uv);
  }
  *(u16x8*)(h + i) = o;
}

// ---------------- 5. down projection: 1-wave blocks, barrier-free ----------------
__global__ __launch_bounds__(64, 3)
void dn_kernel(const u16* __restrict__ hb,
               const float* __restrict__ Wd,
               float* __restrict__ y,
               const int* __restrict__ offs,
               const unsigned* __restrict__ ttab) {
  __shared__ float bsm[32][74];

  int bid = blockIdx.x;                        // 1280 = 8 * 160
  int work = (bid & 7) * 160 + (bid >> 3);
  int mt = work % 40;
  int nt = work / 40;                          // 0..31
  unsigned tv = ttab[mt];
  if (tv == 0xFFFFFFFFu) return;
  int e = tv >> 16, mtl = tv & 0xFFFF;
  int off0 = offs[e];
  int cnt = offs[e+1] - off0;
  int p0 = off0 + mtl * 64;
  int rmax = cnt - mtl * 64 - 1;
  int n0 = nt * 32;

  int l = threadIdx.x;
  int nl = l & 15, hq = l >> 4;
  int kg = hq * 8;
  int ncol = (l & 7) * 4;
  int krow = l >> 3;

  const u16* aptr[4];
#pragma unroll
  for (int mf = 0; mf < 4; ++mf) {
    int r = nl + 16*mf; if (r > rmax) r = rmax;
    aptr[mf] = hb + (size_t)(p0 + r) * FH + kg;
  }
  const float* bsrc = Wd + (size_t)e * FH * DH + (size_t)krow * DH + n0 + ncol;

  f32x4 acc[4][2];
#pragma unroll
  for (int mf = 0; mf < 4; ++mf)
#pragma unroll
    for (int nf = 0; nf < 2; ++nf)
      acc[mf][nf] = f32x4{0.f,0.f,0.f,0.f};

  for (int body = 0; body < 43; ++body) {
    f32x4 bv[8];
#pragma unroll
    for (int i = 0; i < 8; ++i)
      bv[i] = *(const f32x4*)(bsrc + (size_t)(body*64 + i*8) * DH);
    int4 av[4][2];
#pragma unroll
    for (int mf = 0; mf < 4; ++mf) {
      av[mf][0] = *(const int4*)(aptr[mf] + body*64);
      av[mf][1] = *(const int4*)(aptr[mf] + body*64 + 32);
    }
#pragma unroll
    for (int i = 0; i < 8; ++i) {
#pragma unroll
      for (int q = 0; q < 4; ++q)
        bsm[ncol + q][i*8 + krow] = bv[i][q];
    }
#pragma unroll
    for (int h = 0; h < 2; ++h) {
      bf16x8 fb[2];
#pragma unroll
      for (int nf = 0; nf < 2; ++nf) {
#pragma unroll
        for (int j = 0; j < 4; ++j) {
          float2 p = *(const float2*)&bsm[nf*16 + nl][h*32 + kg + 2*j];
          fb[nf][2*j]   = (__bf16)p.x;
          fb[nf][2*j+1] = (__bf16)p.y;
        }
      }
#pragma unroll
      for (int mf = 0; mf < 4; ++mf) {
        bf16x8 a_ = as_bf(av[mf][h]);
        acc[mf][0] = __builtin_amdgcn_mfma_f32_16x16x32_bf16(a_, fb[0], acc[mf][0], 0,0,0);
        acc[mf][1] = __builtin_amdgcn_mfma_f32_16x16x32_bf16(a_, fb[1], acc[mf][1], 0,0,0);
      }
    }
  }

#pragma unroll
  for (int mf = 0; mf < 4; ++mf) {
    int lr0 = hq*4 + mf*16;
#pragma unroll
    for (int nf = 0; nf < 2; ++nf) {
      int col = n0 + nf*16 + nl;
#pragma unroll
      for (int q = 0; q < 4; ++q) {
        int lrow = lr0 + q;
        if (lrow <= rmax)
          y[(size_t)(p0 + lrow) * DH + col] = acc[mf][nf][q];
      }
    }
  }
}

// ---------------- 6. combine ----------------
__global__ void combine_kernel(const float* __restrict__ y,
                               const float* __restrict__ tkw,
                               const int* __restrict__ posf,
                               float* __restrict__ out) {
  int t = blockIdx.x;
  int d = threadIdx.x;
  int pa = posf[t*2], pb = posf[t*2+1];
  float wa = tkw[t*2], wb = tkw[t*2+1];
  f32x4 a0 = ((const f32x4*)(y + (size_t)pa * DH))[d];
  f32x4 b0 = ((const f32x4*)(y + (size_t)pb * DH))[d];
  f32x4 o;
#pragma unroll
  for (int i = 0; i < 4; ++i)
    o[i] = wa*a0[i] + wb*b0[i];
  ((f32x4*)(out + (size_t)t * DH))[d] = o;
}

extern "C" void kernel_launch(void* const* d_in, const int* in_sizes, int n_in,
                              void* d_out, int out_size, void* d_ws, size_t ws_size,
                              hipStream_t stream) {
  const float* x  = (const float*)d_in[0];
  const float* Ws = (const float*)d_in[1];
  const float* bs = (const float*)d_in[2];
  const float* Wg = (const float*)d_in[3];
  const float* Wu = (const float*)d_in[4];
  const float* Wd = (const float*)d_in[5];
  float* out = (float*)d_out;
  char* ws = (char*)d_ws;

  int*      tki  = (int*)     (ws + 0);
  float*    tkw  = (float*)   (ws + 8192);
  int*      offs = (int*)     (ws + 16384);
  unsigned* ttab = (unsigned*)(ws + 16640);      // 40 entries
  int*      posf = (int*)     (ws + 20480);
  int*      rtok = (int*)     (ws + 28672);
  u16*      xb   = (u16*)     (ws + 36864);      // 2 MB
  char*     base2 = ws + 36864 + 2097152;
  u16*      gbuf = (u16*)(base2);                // 2048*2752 bf16 = 11.27 MB
  u16*      ubuf = (u16*)(base2 + 11272192);     // 11.27 MB
  u16*      hbuf = (u16*)(base2 + 2*11272192);   // 11.27 MB
  float*    yws  = (float*)(base2);              // aliases gbuf (dead after swiglu): 8 MB

  gate_kernel<<<256, 256, 0, stream>>>(x, Ws, bs, xb, tki, tkw);
  group_kernel<<<1, 256, 0, stream>>>(tki, offs, rtok, posf, ttab);
  gu_kernel<<<6880, 64, 0, stream>>>(xb, Wg, Wu, gbuf, ubuf, offs, rtok, ttab);
  swiglu_kernel<<<(2048*FH/8)/256, 256, 0, stream>>>(gbuf, ubuf, hbuf);
  dn_kernel<<<1280, 64, 0, stream>>>(hbuf, Wd, yws, offs, ttab);
  combine_kernel<<<NT, 256, 0, stream>>>(yws, tkw, posf, out);
}

// Round 7
// 246.216 us; speedup vs baseline: 1.2053x; 1.2053x over previous
//
#include <hip/hip_runtime.h>

#define DH 1024
#define FH 2752
#define NE 8
#define NT 1024

typedef unsigned short u16;
typedef unsigned int u32;
typedef __bf16 bf16x8 __attribute__((ext_vector_type(8)));
typedef float f32x4 __attribute__((ext_vector_type(4)));

__device__ __forceinline__ u16 f2bf(float f) {
  unsigned int u = __float_as_uint(f);
  unsigned int r = (u + 0x7fffu + ((u >> 16) & 1u)) >> 16;
  return (u16)r;
}
__device__ __forceinline__ float bf2f(u16 b) {
  return __uint_as_float(((unsigned int)b) << 16);
}
__device__ __forceinline__ bf16x8 as_bf(int4 v) {
  union { int4 i; bf16x8 b; } u; u.i = v; return u.b;
}
#define SB0() __builtin_amdgcn_sched_barrier(0)

__device__ __forceinline__ void gload16(const void* g, void* l) {
  __builtin_amdgcn_global_load_lds(
      (const __attribute__((address_space(1))) u32*)g,
      (__attribute__((address_space(3))) u32*)l, 16, 0, 0);
}

// ---------------- 1. gating ----------------
__global__ void gate_kernel(const float* __restrict__ x,
                            const float* __restrict__ Ws,
                            const float* __restrict__ bs,
                            u16* __restrict__ xb,
                            int* __restrict__ tki,
                            float* __restrict__ tkw) {
  int gtid = blockIdx.x * blockDim.x + threadIdx.x;
  int t = gtid >> 6;
  int lane = gtid & 63;
  if (t >= NT) return;
  const float* xr = x + (size_t)t * DH;
  float acc[NE];
#pragma unroll
  for (int e = 0; e < NE; ++e) acc[e] = 0.f;
  for (int d = lane; d < DH; d += 64) {
    float xv = xr[d];
    xb[(size_t)t * DH + d] = f2bf(xv);
    const float4* wr = (const float4*)(Ws + (size_t)d * NE);
    float4 w0 = wr[0], w1 = wr[1];
    acc[0] += xv * w0.x; acc[1] += xv * w0.y;
    acc[2] += xv * w0.z; acc[3] += xv * w0.w;
    acc[4] += xv * w1.x; acc[5] += xv * w1.y;
    acc[6] += xv * w1.z; acc[7] += xv * w1.w;
  }
#pragma unroll
  for (int e = 0; e < NE; ++e) {
#pragma unroll
    for (int off = 32; off > 0; off >>= 1)
      acc[e] += __shfl_xor(acc[e], off);
  }
  if (lane == 0) {
    float l[NE];
#pragma unroll
    for (int e = 0; e < NE; ++e) l[e] = acc[e] + bs[e];
    int i0 = 0;
#pragma unroll
    for (int e = 1; e < NE; ++e) if (l[e] > l[i0]) i0 = e;
    int i1 = (i0 == 0) ? 1 : 0;
#pragma unroll
    for (int e = 0; e < NE; ++e) if (e != i0 && l[e] > l[i1]) i1 = e;
    float e1 = __expf(l[i1] - l[i0]);
    float denom = 1.f + e1;
    tki[t*2]   = i0; tki[t*2+1] = i1;
    tkw[t*2]   = 1.f / denom;
    tkw[t*2+1] = e1 / denom;
  }
}

// ---------------- 2. expert grouping + 256-row tile table ----------------
__global__ void group_kernel(const int* __restrict__ tki,
                             int* __restrict__ offs,
                             int* __restrict__ rtok,
                             int* __restrict__ posf,
                             unsigned* __restrict__ ttab) {
  __shared__ int cnt[NE];
  __shared__ int run[NE];
  int tid = threadIdx.x;
  if (tid < NE) cnt[tid] = 0;
  __syncthreads();
  for (int t = tid; t < NT; t += blockDim.x) {
    atomicAdd(&cnt[tki[t*2]], 1);
    atomicAdd(&cnt[tki[t*2+1]], 1);
  }
  __syncthreads();
  if (tid == 0) {
    int r = 0;
    for (int e = 0; e < NE; ++e) { offs[e] = r; run[e] = r; r += cnt[e]; }
    offs[NE] = r;
    int idx = 0;
    for (int e = 0; e < NE; ++e) {
      int nt256 = (cnt[e] + 255) >> 8;
      for (int m = 0; m < nt256; ++m) ttab[idx++] = ((unsigned)e << 16) | (unsigned)m;
    }
    for (; idx < 16; ++idx) ttab[idx] = 0xFFFFFFFFu;
  }
  __syncthreads();
  for (int t = tid; t < NT; t += blockDim.x) {
    for (int k = 0; k < 2; ++k) {
      int e = tki[t*2+k];
      int p = atomicAdd(&run[e], 1);
      rtok[p] = t;
      posf[t*2+k] = p;
    }
  }
}

// ---------------- 3. fused gate+up+SwiGLU GEMM, global_load_lds staging ------
// BM=256 x BN=32, BK=64, 4 waves. A: global->reg 1-deep. B(Wg,Wu) fp32 via
// global_load_lds into 3 rotating buffers, issued 2 tiles ahead, counted vmcnt.
// LDS linear (required); XOR-16 column swizzle applied to the GLOBAL source so
// fragment b32 reads are 2-way conflict-free. fp32->bf16 at fragment build.
__global__ __launch_bounds__(256, 2)
void gu_kernel(const u16* __restrict__ xb,
               const float* __restrict__ Wg,
               const float* __restrict__ Wu,
               u16* __restrict__ hbuf,
               const int* __restrict__ offs,
               const int* __restrict__ rtok,
               const unsigned* __restrict__ ttab) {
  __shared__ float bsm[3][2][2048];   // 3 bufs x {g,u} x 64k*32n fp32 = 48 KB

  int bid = blockIdx.x;                       // 1376 = 8 * 172
  int work = (bid & 7) * 172 + (bid >> 3);    // XCD-chunked
  int mt = work / 86, ntile = work - mt * 86;
  unsigned tv = ttab[mt];
  if (tv == 0xFFFFFFFFu) return;
  int e = tv >> 16, mtl = tv & 0xFFFF;
  int off0 = offs[e], cnt = offs[e + 1] - off0;
  int p0 = off0 + mtl * 256, rmax = cnt - mtl * 256 - 1;
  int n0 = ntile * 32;
  int tid = threadIdx.x, lane = tid & 63, wv = tid >> 6;
  int q = lane >> 4, nl = lane & 15, kg = q * 8;

  const u16* aptr[4];
#pragma unroll
  for (int mf = 0; mf < 4; ++mf) {
    int r = wv * 64 + nl + mf * 16;
    if (r > rmax) r = rmax;
    aptr[mf] = xb + (size_t)rtok[p0 + r] * DH + kg;
  }

  const float* wsrc0 = Wg + (size_t)e * DH * FH;
  const float* wsrc1 = Wu + (size_t)e * DH * FH;
  int g0 = 2 * wv, g1 = 2 * wv + 1;          // this wave's 1KB chunks
  int gr0 = 8 * g0 + (lane >> 3);            // k-row within tile
  int gr1 = 8 * g1 + (lane >> 3);
  int gc0 = n0 + ((lane & 7) * 4);           // even chunk: no swizzle
  int gc1 = n0 + (((lane & 7) * 4) ^ 16);    // odd chunk: XOR-16 col swizzle

#define GU_STAGE(KT, BUF) {                                                    \
    gload16(wsrc0 + (size_t)((KT)*64 + gr0) * FH + gc0, (char*)&bsm[BUF][0][0] + g0*1024); \
    gload16(wsrc0 + (size_t)((KT)*64 + gr1) * FH + gc1, (char*)&bsm[BUF][0][0] + g1*1024); \
    gload16(wsrc1 + (size_t)((KT)*64 + gr0) * FH + gc0, (char*)&bsm[BUF][1][0] + g0*1024); \
    gload16(wsrc1 + (size_t)((KT)*64 + gr1) * FH + gc1, (char*)&bsm[BUF][1][0] + g1*1024); }

#define GU_LOADA(DST, KT) {                                                    \
    _Pragma("unroll") for (int mf = 0; mf < 4; ++mf) {                         \
      DST[mf][0] = *(const int4*)(aptr[mf] + (KT)*64);                         \
      DST[mf][1] = *(const int4*)(aptr[mf] + (KT)*64 + 32); } }

  f32x4 accg[4][2], accu[4][2];
#pragma unroll
  for (int mf = 0; mf < 4; ++mf)
#pragma unroll
    for (int nf = 0; nf < 2; ++nf) {
      accg[mf][nf] = f32x4{0.f,0.f,0.f,0.f};
      accu[mf][nf] = f32x4{0.f,0.f,0.f,0.f};
    }

  int4 Areg[2][4][2];

  // prologue: G(0), A(0), G(1)  (order matters for vmcnt counting)
  GU_STAGE(0, 0); SB0();
  GU_LOADA(Areg[0], 0); SB0();
  GU_STAGE(1, 1); SB0();

  int cw0 = nl ^ ((q & 1) << 4);    // nf=0 swizzled col
  int cw1 = cw0 ^ 16;               // nf=1

#define GU_MAT(BP, ACC, AT) {                                                  \
    bf16x8 fr[2][2];                                                           \
    _Pragma("unroll") for (int h = 0; h < 2; ++h) {                            \
      _Pragma("unroll") for (int nf = 0; nf < 2; ++nf) {                       \
        const float* rp = (BP) + (size_t)(h * 32 + kg) * 32 + (nf ? cw1 : cw0);\
        _Pragma("unroll") for (int j = 0; j < 8; ++j)                          \
          fr[h][nf][j] = (__bf16)rp[j * 32];                                   \
      } }                                                                      \
    _Pragma("unroll") for (int h = 0; h < 2; ++h)                              \
      _Pragma("unroll") for (int mf = 0; mf < 4; ++mf) {                       \
        bf16x8 av = as_bf(AT[mf][h]);                                          \
        ACC[mf][0] = __builtin_amdgcn_mfma_f32_16x16x32_bf16(av, fr[h][0], ACC[mf][0], 0,0,0); \
        ACC[mf][1] = __builtin_amdgcn_mfma_f32_16x16x32_bf16(av, fr[h][1], ACC[mf][1], 0,0,0); \
      } }

#pragma unroll
  for (int t = 0; t < 16; ++t) {
    __builtin_amdgcn_s_barrier();
    SB0();
    if (t + 1 < 16) { GU_LOADA(Areg[(t + 1) & 1], t + 1); }
    SB0();
    if (t + 2 < 16) { GU_STAGE(t + 2, (t + 2) % 3); }
    SB0();
    // N = outstanding-after-G(t) = A(t) + G(t+1) + A(t+1) + G(t+2)
    if (t <= 13)      { asm volatile("s_waitcnt vmcnt(24)" ::: "memory"); }
    else if (t == 14) { asm volatile("s_waitcnt vmcnt(20)" ::: "memory"); }
    else              { asm volatile("s_waitcnt vmcnt(8)"  ::: "memory"); }
    SB0();
    const float* bg = &bsm[t % 3][0][0];
    const float* bu = &bsm[t % 3][1][0];
    GU_MAT(bg, accg, Areg[t & 1]);
    GU_MAT(bu, accu, Areg[t & 1]);
  }

  // epilogue: h = silu(g)*u, bf16
#pragma unroll
  for (int mf = 0; mf < 4; ++mf) {
    int lr0 = wv*64 + q*4 + mf*16;
#pragma unroll
    for (int nf = 0; nf < 2; ++nf) {
      int col = n0 + nf*16 + nl;
#pragma unroll
      for (int qq = 0; qq < 4; ++qq) {
        int lrow = lr0 + qq;
        if (lrow <= rmax) {
          float g = accg[mf][nf][qq], u = accu[mf][nf][qq];
          float s = g / (1.f + __expf(-g));
          hbuf[(size_t)(p0 + lrow) * FH + col] = f2bf(s * u);
        }
      }
    }
  }
}

// ---------------- 4. down projection, K-split=2, same staging ----------------
template<int NIT, int KT0>
__device__ __forceinline__ void dn_core(const u16* __restrict__ hb,
                                        const float* __restrict__ Wd,
                                        float* __restrict__ y,
                                        int e, int p0, int rmax, int n0,
                                        float (*bsm)[2048]) {
  int tid = threadIdx.x, lane = tid & 63, wv = tid >> 6;
  int q = lane >> 4, nl = lane & 15, kg = q * 8;

  const u16* aptr[4];
#pragma unroll
  for (int mf = 0; mf < 4; ++mf) {
    int r = wv * 64 + nl + mf * 16;
    if (r > rmax) r = rmax;
    aptr[mf] = hb + (size_t)(p0 + r) * FH + KT0 + kg;
  }

  const float* wsrc = Wd + (size_t)e * FH * DH;
  int g0 = 2 * wv, g1 = 2 * wv + 1;
  int gr0 = 8 * g0 + (lane >> 3);
  int gr1 = 8 * g1 + (lane >> 3);
  int gc0 = n0 + ((lane & 7) * 4);
  int gc1 = n0 + (((lane & 7) * 4) ^ 16);

#define DN_STAGE(KT, BUF) {                                                    \
    gload16(wsrc + (size_t)(KT0 + (KT)*64 + gr0) * DH + gc0, (char*)&bsm[BUF][0] + g0*1024); \
    gload16(wsrc + (size_t)(KT0 + (KT)*64 + gr1) * DH + gc1, (char*)&bsm[BUF][0] + g1*1024); }

#define DN_LOADA(DST, KT) {                                                    \
    _Pragma("unroll") for (int mf = 0; mf < 4; ++mf) {                         \
      DST[mf][0] = *(const int4*)(aptr[mf] + (KT)*64);                         \
      DST[mf][1] = *(const int4*)(aptr[mf] + (KT)*64 + 32); } }

  f32x4 acc[4][2];
#pragma unroll
  for (int mf = 0; mf < 4; ++mf)
#pragma unroll
    for (int nf = 0; nf < 2; ++nf)
      acc[mf][nf] = f32x4{0.f,0.f,0.f,0.f};

  int4 Areg[2][4][2];

  DN_STAGE(0, 0); SB0();
  DN_LOADA(Areg[0], 0); SB0();
  DN_STAGE(1, 1); SB0();

  int cw0 = nl ^ ((q & 1) << 4);
  int cw1 = cw0 ^ 16;

#pragma unroll
  for (int t = 0; t < NIT; ++t) {
    __builtin_amdgcn_s_barrier();
    SB0();
    if (t + 1 < NIT) { DN_LOADA(Areg[(t + 1) & 1], t + 1); }
    SB0();
    if (t + 2 < NIT) { DN_STAGE(t + 2, (t + 2) % 3); }
    SB0();
    if (t <= NIT - 3)      { asm volatile("s_waitcnt vmcnt(20)" ::: "memory"); }
    else if (t == NIT - 2) { asm volatile("s_waitcnt vmcnt(18)" ::: "memory"); }
    else                   { asm volatile("s_waitcnt vmcnt(8)"  ::: "memory"); }
    SB0();
    const float* bp = &bsm[t % 3][0];
    bf16x8 fr[2][2];
#pragma unroll
    for (int h = 0; h < 2; ++h) {
#pragma unroll
      for (int nf = 0; nf < 2; ++nf) {
        const float* rp = bp + (size_t)(h * 32 + kg) * 32 + (nf ? cw1 : cw0);
#pragma unroll
        for (int j = 0; j < 8; ++j)
          fr[h][nf][j] = (__bf16)rp[j * 32];
      }
    }
#pragma unroll
    for (int h = 0; h < 2; ++h)
#pragma unroll
      for (int mf = 0; mf < 4; ++mf) {
        bf16x8 av = as_bf(Areg[t & 1][mf][h]);
        acc[mf][0] = __builtin_amdgcn_mfma_f32_16x16x32_bf16(av, fr[h][0], acc[mf][0], 0,0,0);
        acc[mf][1] = __builtin_amdgcn_mfma_f32_16x16x32_bf16(av, fr[h][1], acc[mf][1], 0,0,0);
      }
  }

#pragma unroll
  for (int mf = 0; mf < 4; ++mf) {
    int lr0 = wv*64 + q*4 + mf*16;
#pragma unroll
    for (int nf = 0; nf < 2; ++nf) {
      int col = n0 + nf*16 + nl;
#pragma unroll
      for (int qq = 0; qq < 4; ++qq) {
        int lrow = lr0 + qq;
        if (lrow <= rmax)
          y[(size_t)(p0 + lrow) * DH + col] = acc[mf][nf][qq];
      }
    }
  }
}

__global__ __launch_bounds__(256, 2)
void dn_kernel(const u16* __restrict__ hb,
               const float* __restrict__ Wd,
               float* __restrict__ y,
               const int* __restrict__ offs,
               const unsigned* __restrict__ ttab) {
  __shared__ float bsm[3][2048];   // 24 KB

  int bid = blockIdx.x;                      // 1024 = 8 * 128
  int work = (bid & 7) * 128 + (bid >> 3);
  int mt = work >> 6, r = work & 63, nt = r & 31, ks = r >> 5;
  unsigned tv = ttab[mt];
  if (tv == 0xFFFFFFFFu) return;
  int e = tv >> 16, mtl = tv & 0xFFFF;
  int off0 = offs[e], cnt = offs[e+1] - off0;
  int p0 = off0 + mtl * 256, rmax = cnt - mtl * 256 - 1;
  int n0 = nt * 32;
  if (ks == 0) dn_core<22, 0>(hb, Wd, y, e, p0, rmax, n0, bsm);
  else         dn_core<21, 1408>(hb, Wd, y + (size_t)2048 * DH, e, p0, rmax, n0, bsm);
}

// ---------------- 5. combine ----------------
__global__ void combine_kernel(const float* __restrict__ y,
                               const float* __restrict__ tkw,
                               const int* __restrict__ posf,
                               float* __restrict__ out) {
  int t = blockIdx.x;
  int d = threadIdx.x;
  const float* y1 = y + (size_t)2048 * DH;
  int pa = posf[t*2], pb = posf[t*2+1];
  float wa = tkw[t*2], wb = tkw[t*2+1];
  f32x4 a0 = ((const f32x4*)(y  + (size_t)pa * DH))[d];
  f32x4 a1 = ((const f32x4*)(y1 + (size_t)pa * DH))[d];
  f32x4 b0 = ((const f32x4*)(y  + (size_t)pb * DH))[d];
  f32x4 b1 = ((const f32x4*)(y1 + (size_t)pb * DH))[d];
  f32x4 o;
#pragma unroll
  for (int i = 0; i < 4; ++i)
    o[i] = wa*(a0[i]+a1[i]) + wb*(b0[i]+b1[i]);
  ((f32x4*)(out + (size_t)t * DH))[d] = o;
}

extern "C" void kernel_launch(void* const* d_in, const int* in_sizes, int n_in,
                              void* d_out, int out_size, void* d_ws, size_t ws_size,
                              hipStream_t stream) {
  const float* x  = (const float*)d_in[0];
  const float* Ws = (const float*)d_in[1];
  const float* bs = (const float*)d_in[2];
  const float* Wg = (const float*)d_in[3];
  const float* Wu = (const float*)d_in[4];
  const float* Wd = (const float*)d_in[5];
  float* out = (float*)d_out;
  char* ws = (char*)d_ws;

  int*      tki  = (int*)     (ws + 0);
  float*    tkw  = (float*)   (ws + 8192);
  int*      offs = (int*)     (ws + 16384);
  unsigned* ttab = (unsigned*)(ws + 16640);      // 16 entries
  int*      posf = (int*)     (ws + 20480);
  int*      rtok = (int*)     (ws + 28672);
  u16*      xb   = (u16*)     (ws + 36864);      // 2 MB
  char*     base2 = ws + 36864 + 2097152;
  u16*      hbuf = (u16*)(base2);                // 2048*2752 bf16 = 11.27 MB
  float*    yws  = (float*)(base2 + 11272192);   // 2 * 2048*1024 f32 = 16 MB

  gate_kernel<<<256, 256, 0, stream>>>(x, Ws, bs, xb, tki, tkw);
  group_kernel<<<1, 256, 0, stream>>>(tki, offs, rtok, posf, ttab);
  gu_kernel<<<1376, 256, 0, stream>>>(xb, Wg, Wu, hbuf, offs, rtok, ttab);
  dn_kernel<<<1024, 256, 0, stream>>>(hbuf, Wd, yws, offs, ttab);
  combine_kernel<<<NT, 256, 0, stream>>>(yws, tkw, posf, out);
}